// Round 7
// baseline (411.856 us; speedup 1.0000x reference)
//
#include <hip/hip_runtime.h>
#include <hip/hip_bf16.h>
#include <hip/hip_fp16.h>
#include <math.h>

// QAT GPT2 MLP + LoRA on MI355X — fp32 in/out.
// Round 12: resubmit of round-11 (bench infra failed: "container failed
// twice"; no kernel signal). Audited for hang vectors: barrier structure
// identical to round-2/3 (passed), swapped-operand layout re-derived
// (mfma(b,a): lane holds C[m=l15][n=quad*4+r], stores 8B/16B aligned),
// fused launcher kernels barrier-free. Content: round-2 8-phase 256^2 GEMM
// schedule (measured best 80.5us) + swapped-operand MFMA for packed
// epilogue stores + launch fusion (absmax3 / quant_w2 / conv_a16x2).
// Fused quant_x_t1 / quant_h_t2 (MFMA LoRA-t, chunked in-place i8) kept.

typedef unsigned short u16;
typedef unsigned int u32;
typedef signed char i8;
typedef int i32x4 __attribute__((ext_vector_type(4)));
typedef _Float16 f16;
typedef f16 f16x8 __attribute__((ext_vector_type(8)));
typedef float f32x4 __attribute__((ext_vector_type(4)));

#define ASYNC16(gp, lp)                                                        \
  __builtin_amdgcn_global_load_lds(                                            \
      (__attribute__((address_space(1))) void*)(gp),                           \
      (__attribute__((address_space(3))) void*)(lp), 16, 0, 0)

#define VMCNT(N) asm volatile("s_waitcnt vmcnt(" #N ")" ::: "memory")
#define LGKM0                                                                  \
  do {                                                                         \
    asm volatile("s_waitcnt lgkmcnt(0)" ::: "memory");                         \
    __builtin_amdgcn_sched_barrier(0);                                         \
  } while (0)
#define SBAR __builtin_amdgcn_s_barrier()

// quantize to int: q = clip(rint(v/s), -128, 127)
__device__ __forceinline__ int quanti(float v, float inv) {
  float q = rintf(v * inv);
  q = fminf(fmaxf(q, -128.0f), 127.0f);
  return (int)q;
}

__device__ __forceinline__ u32 pack4(float4 v, float inv) {
  return ((u32)(quanti(v.x, inv) & 255)) |
         ((u32)(quanti(v.y, inv) & 255) << 8) |
         ((u32)(quanti(v.z, inv) & 255) << 16) |
         ((u32)(quanti(v.w, inv) & 255) << 24);
}

__device__ __forceinline__ float load_scale(const u32* slot) {
  return fmaxf(__uint_as_float(*slot) * (1.0f / 127.0f), 1e-8f);
}

// exact-erf GELU via Abramowitz-Stegun 7.1.26 (|erf err| <= 1.5e-7)
__device__ __forceinline__ float gelu_erf(float v) {
  float z = fabsf(v) * 0.70710678118654752f;
  float t = __builtin_amdgcn_rcpf(fmaf(0.3275911f, z, 1.0f));
  float poly =
      t * fmaf(t,
               fmaf(t,
                    fmaf(t, fmaf(t, 1.061405429f, -1.453152027f),
                         1.421413741f),
                    -0.284496736f),
               0.254829592f);
  float e = fmaf(-poly, exp2f(-z * z * 1.4426950408889634f), 1.0f);
  return 0.5f * v * fmaf(copysignf(e, v), 1.0f, 1.0f);
}

// ---- fused absmax over 3 fp32 tensors (blockIdx.y selects) -----------------
__global__ void absmax3_kernel(const float* __restrict__ t0, int n0,
                               const float* __restrict__ t1, int n1,
                               const float* __restrict__ t2, int n2,
                               u32* __restrict__ slots) {
  const float* x;
  int n4;
  u32* slot;
  if (blockIdx.y == 0) { x = t0; n4 = n0; slot = slots + 0; }
  else if (blockIdx.y == 1) { x = t1; n4 = n1; slot = slots + 1; }
  else { x = t2; n4 = n2; slot = slots + 2; }
  float m = 0.0f;
  int stride = gridDim.x * blockDim.x;
  for (int i = blockIdx.x * blockDim.x + threadIdx.x; i < n4; i += stride) {
    float4 v = ((const float4*)x)[i];
    m = fmaxf(m, fmaxf(fmaxf(fabsf(v.x), fabsf(v.y)),
                       fmaxf(fabsf(v.z), fabsf(v.w))));
  }
#pragma unroll
  for (int off = 32; off > 0; off >>= 1) m = fmaxf(m, __shfl_down(m, off));
  __shared__ float wmax[4];
  int lane = threadIdx.x & 63, wave = threadIdx.x >> 6;
  if (lane == 0) wmax[wave] = m;
  __syncthreads();
  if (threadIdx.x == 0) {
    m = fmaxf(fmaxf(wmax[0], wmax[1]), fmaxf(wmax[2], wmax[3]));
    atomicMax(slot, __float_as_uint(m));  // positive floats: bit-monotone
  }
}

// ---------------- quantize both W (fp32 in, packed i8 out) ------------------
__global__ void quant_w2_kernel(const float* __restrict__ w0,
                                const float* __restrict__ w1, int n16,
                                const u32* __restrict__ slots,
                                i8* __restrict__ q0, i8* __restrict__ q1) {
  const float* w = blockIdx.y ? w1 : w0;
  i8* q = blockIdx.y ? q1 : q0;
  float inv = 1.0f / load_scale(slots + 1 + blockIdx.y);
  int stride = gridDim.x * blockDim.x;
  for (int i = blockIdx.x * blockDim.x + threadIdx.x; i < n16; i += stride) {
    const float4* src = (const float4*)w + i * 4;
    u32 pk[4];
#pragma unroll
    for (int c = 0; c < 4; c++) pk[c] = pack4(src[c], inv);
    uint4 o = {pk[0], pk[1], pk[2], pk[3]};
    ((uint4*)q)[i] = o;
  }
}

// ---- convert both A [8][ncols] fp32 -> [16][ncols] fp16, rows 8-15 zero ----
__global__ void conv_a16x2_kernel(const float* __restrict__ A0,
                                  f16* __restrict__ Ah0,  // ncols 4096
                                  const float* __restrict__ A1,
                                  f16* __restrict__ Ah1) {  // ncols 1024
  const float* A = blockIdx.y ? A1 : A0;
  f16* Ah = blockIdx.y ? Ah1 : Ah0;
  int ncols = blockIdx.y ? 1024 : 4096;
  int i = blockIdx.x * blockDim.x + threadIdx.x;
  int base = i * 8;
  if (base >= 16 * ncols) return;
  if (base < 8 * ncols) {
    float4 v0 = ((const float4*)(A + base))[0];
    float4 v1 = ((const float4*)(A + base))[1];
    f16x8 o = {(f16)v0.x, (f16)v0.y, (f16)v0.z, (f16)v0.w,
               (f16)v1.x, (f16)v1.y, (f16)v1.z, (f16)v1.w};
    *(f16x8*)(Ah + base) = o;
  } else {
    f16x8 z = {};
    *(f16x8*)(Ah + base) = z;
  }
}

// ---- fused: quantize x (fp32 -> i8, exact) + t1 = x.Afc^T via fp16 MFMA ----
__launch_bounds__(256) __global__
    void quant_x_t1_fused(const float* __restrict__ x,   // [8192][1024]
                          const f16* __restrict__ Ah,    // [16][1024]
                          const u32* __restrict__ slot,
                          i8* __restrict__ xq,           // [8192][1024]
                          float* __restrict__ t1) {      // [8192][8], zeroed
  int tid = threadIdx.x;
  int lane = tid & 63, wave = tid >> 6;
  int quad = lane >> 4, l15 = lane & 15;
  int bx = blockIdx.x;                       // k-chunk [0,2)
  long m0 = (long)blockIdx.y * 64 + wave * 16;
  long row = m0 + l15;
  int k0 = bx * 512;
  float inv = 1.0f / load_scale(slot);

  const float* xp = x + row * 1024 + k0 + quad * 8;
  const f16* ap = Ah + l15 * 1024 + k0 + quad * 8;
  i8* op = xq + row * 1024 + k0 + quad * 8;
  f32x4 acc = {0.0f, 0.0f, 0.0f, 0.0f};
#pragma unroll
  for (int s = 0; s < 16; s++) {
    float4 v0 = ((const float4*)(xp + s * 32))[0];
    float4 v1 = ((const float4*)(xp + s * 32))[1];
    f16x8 af = {(f16)v0.x, (f16)v0.y, (f16)v0.z, (f16)v0.w,
                (f16)v1.x, (f16)v1.y, (f16)v1.z, (f16)v1.w};
    f16x8 bf = *(const f16x8*)(ap + s * 32);
    acc = __builtin_amdgcn_mfma_f32_16x16x32_f16(af, bf, acc, 0, 0, 0);
    uint2 o = {pack4(v0, inv), pack4(v1, inv)};
    *(uint2*)(op + s * 32) = o;
  }
  if (l15 < 8) {
#pragma unroll
    for (int r = 0; r < 4; r++) {
      long m = m0 + quad * 4 + r;
      atomicAdd(&t1[m * 8 + l15], acc[r]);
    }
  }
}

// ---- fused: quantize h (fp16 -> i8 in place, chunked) + t2 = h.A^T via MFMA
__launch_bounds__(256) __global__
    void quant_h_t2_fused(u16* __restrict__ h,        // [8192][4096] fp16
                          const f16* __restrict__ Ah, // [16][4096]
                          const u32* __restrict__ slot,
                          float* __restrict__ t2) {   // [8192][8], pre-zeroed
  int tid = threadIdx.x;
  int lane = tid & 63, wave = tid >> 6;
  int quad = lane >> 4, l15 = lane & 15;
  int bx = blockIdx.x;                       // k-chunk index [0,8)
  long m0 = (long)blockIdx.y * 64 + wave * 16;
  long row = m0 + l15;
  int k0 = bx * 512;
  float inv = 1.0f / load_scale(slot);

  const u16* hp = h + row * 4096 + k0 + quad * 8;
  const f16* ap = Ah + l15 * 4096 + k0 + quad * 8;
  f32x4 acc = {0.0f, 0.0f, 0.0f, 0.0f};
  u32 q[32];
#pragma unroll
  for (int s = 0; s < 16; s++) {
    uint4 hv = *(const uint4*)(hp + s * 32);   // 8 fp16 of h
    f16x8 af = *(const f16x8*)&hv;
    f16x8 bf = *(const f16x8*)(ap + s * 32);
    acc = __builtin_amdgcn_mfma_f32_16x16x32_f16(af, bf, acc, 0, 0, 0);
    u32 uu[4] = {hv.x, hv.y, hv.z, hv.w};
#pragma unroll
    for (int c = 0; c < 2; c++) {
      float2 f0 = __half22float2(*(__half2*)&uu[2 * c]);
      float2 f1 = __half22float2(*(__half2*)&uu[2 * c + 1]);
      q[2 * s + c] = ((u32)(quanti(f0.x, inv) & 255)) |
                     ((u32)(quanti(f0.y, inv) & 255) << 8) |
                     ((u32)(quanti(f1.x, inv) & 255) << 16) |
                     ((u32)(quanti(f1.y, inv) & 255) << 24);
    }
  }
  asm volatile("" ::: "memory");
  i8* op = (i8*)h + row * 8192 + bx * 1024 + quad * 8;
#pragma unroll
  for (int s = 0; s < 16; s++) {
    uint2 o = {q[2 * s], q[2 * s + 1]};
    *(uint2*)(op + s * 32) = o;
  }
  if (l15 < 8) {
#pragma unroll
    for (int r = 0; r < 4; r++) {
      long m = m0 + quad * 4 + r;
      atomicAdd(&t2[m * 8 + l15], acc[r]);
    }
  }
}

// ---------- 8-phase pipelined i8 GEMM: C = Aq * Bq^T, BM=256, BK=128 --------
// Round-2 schedule verbatim (measured best: 80.5us gemm1). MFMA operands
// SWAPPED: acc[i][j] = mfma(b[j], a[i], acc) -> each C-tile transposed in
// lanes: lane(quad,l15) holds m = wm+i*16+l15, n = wn+j*16+quad*4+r.
// Epilogue: packed stores (uint2 fp16 / float4 fp32), Bl block-contiguous.
template <int MODE, int BN, int WARPS_M>
__launch_bounds__(512, 2) __global__
    void gemm8p_kernel(const i8* __restrict__ A, const i8* __restrict__ B,
                       int N, int K, int lda, int ldb,
                       const float* __restrict__ bias,
                       const float* __restrict__ tl,   // [M][8] f32
                       const float* __restrict__ Bl,   // [N][8] f32
                       const u32* __restrict__ scales, int sa, int sb,
                       void* __restrict__ outp, u32* __restrict__ hmax) {
  constexpr int WARPS_N = 8 / WARPS_M;
  constexpr int MT = 256 / (16 * WARPS_M);   // m-tiles per wave
  constexpr int NT = BN / (16 * WARPS_N);    // n-tiles per wave
  constexpr int LB = BN / 128;               // B loads per half per thread
  __shared__ __align__(16) i8 As[2][256 * 128];
  __shared__ __align__(16) i8 Bs[2][BN * 128];
  __shared__ u32 bmax;
  int tid = threadIdx.x;
  int lane = tid & 63, wave = tid >> 6;
  int quad = lane >> 4, l15 = lane & 15;
  int wm = (wave % WARPS_M) * (MT * 16);
  int wn = (wave / WARPS_M) * (NT * 16);
  // XCD-bijective swizzle (nwg % 8 == 0 for both grids)
  int nwg = gridDim.x * gridDim.y;
  int lin = blockIdx.y * gridDim.x + blockIdx.x;
  int swb = (lin & 7) * (nwg >> 3) + (lin >> 3);
  int bx = swb % gridDim.x, by = swb / gridDim.x;
  long m0 = (long)by * 256;
  long n0 = (long)bx * BN;
  if (MODE == 0 && tid == 0) bmax = 0u;

  const i8* pA[2];
  int ldsA[2];
#pragma unroll
  for (int u = 0; u < 2; u++) {
    int c = u * 512 + tid;
    int row = c >> 3;
    int swz = ((c & 7) ^ (row & 7)) * 16;
    pA[u] = A + (m0 + row) * lda + swz;
    ldsA[u] = c * 16;
  }
  const i8* pB[LB];
  int ldsB[LB];
#pragma unroll
  for (int u = 0; u < LB; u++) {
    int c = u * 512 + tid;
    int row = c >> 3;
    int swz = ((c & 7) ^ (row & 7)) * 16;
    pB[u] = B + (n0 + row) * ldb + swz;
    ldsB[u] = c * 16;
  }

  auto stageA = [&](int t, int h) {
    int kb = (MODE == 1) ? ((t >> 2) * 1024 + (t & 3) * 128) : (t << 7);
    int bb = t & 1;
#pragma unroll
    for (int u = 0; u < 2; u++)
      ASYNC16(pA[u] + (long)h * 128 * lda + kb,
              &As[bb][h * 16384 + ldsA[u]]);
  };
  auto stageB = [&](int t, int h) {
    int kb = t << 7;
    int bb = t & 1;
#pragma unroll
    for (int u = 0; u < LB; u++)
      ASYNC16(pB[u] + (long)h * (BN / 2) * ldb + kb,
              &Bs[bb][h * (BN / 2) * 128 + ldsB[u]]);
  };

  // fragment-read swizzled chunk byte offsets: chunk = (kk*4+quad)^(l15&7)
  int s0 = (quad ^ (l15 & 7)) * 16;
  int s1 = s0 ^ 64;

  i32x4 acc[MT][NT] = {};
  int NTILES = K >> 7;

  // prologue: tile0 fully + tile1 A-halves; then wait tile0 (4 may fly)
  stageA(0, 0); stageA(0, 1); stageB(0, 0); stageB(0, 1);
  stageA(1, 0); stageA(1, 1);
  VMCNT(4);
  SBAR;

  for (int t = 0; t < NTILES; t++) {
    const i8* Ab = As[t & 1];
    const i8* Bb = Bs[t & 1];
    i32x4 a0[MT], a1[MT], b0[NT], b1[NT];
    // ---- phase 1: read A[kk0]+B[kk0]; stage B-h0(t+1); MFMA kk0, mhalf0
#pragma unroll
    for (int i = 0; i < MT; i++)
      a0[i] = *(const i32x4*)(Ab + (wm + i * 16 + l15) * 128 + s0);
#pragma unroll
    for (int j = 0; j < NT; j++)
      b0[j] = *(const i32x4*)(Bb + (wn + j * 16 + l15) * 128 + s0);
    if (t + 1 < NTILES) stageB(t + 1, 0);
    SBAR;
    LGKM0;
    __builtin_amdgcn_s_setprio(1);
#pragma unroll
    for (int i = 0; i < MT / 2; i++)
#pragma unroll
      for (int j = 0; j < NT; j++)
        acc[i][j] = __builtin_amdgcn_mfma_i32_16x16x64_i8(b0[j], a0[i],
                                                          acc[i][j], 0, 0, 0);
    __builtin_amdgcn_s_setprio(0);
    SBAR;
    // ---- phase 2: read A[kk1]; stage B-h1(t+1); MFMA kk0, mhalf1
#pragma unroll
    for (int i = 0; i < MT; i++)
      a1[i] = *(const i32x4*)(Ab + (wm + i * 16 + l15) * 128 + s1);
    if (t + 1 < NTILES) stageB(t + 1, 1);
    SBAR;
    LGKM0;
    __builtin_amdgcn_s_setprio(1);
#pragma unroll
    for (int i = MT / 2; i < MT; i++)
#pragma unroll
      for (int j = 0; j < NT; j++)
        acc[i][j] = __builtin_amdgcn_mfma_i32_16x16x64_i8(b0[j], a0[i],
                                                          acc[i][j], 0, 0, 0);
    __builtin_amdgcn_s_setprio(0);
    SBAR;
    // ---- phase 3: read B[kk1]; stage A-h0(t+2); MFMA kk1, mhalf0
#pragma unroll
    for (int j = 0; j < NT; j++)
      b1[j] = *(const i32x4*)(Bb + (wn + j * 16 + l15) * 128 + s1);
    if (t + 2 < NTILES) stageA(t + 2, 0);
    SBAR;
    LGKM0;
    __builtin_amdgcn_s_setprio(1);
#pragma unroll
    for (int i = 0; i < MT / 2; i++)
#pragma unroll
      for (int j = 0; j < NT; j++)
        acc[i][j] = __builtin_amdgcn_mfma_i32_16x16x64_i8(b1[j], a1[i],
                                                          acc[i][j], 0, 0, 0);
    __builtin_amdgcn_s_setprio(0);
    SBAR;
    // ---- phase 4: stage A-h1(t+2); MFMA kk1, mhalf1; counted vmcnt
    if (t + 2 < NTILES) stageA(t + 2, 1);
    SBAR;
    __builtin_amdgcn_s_setprio(1);
#pragma unroll
    for (int i = MT / 2; i < MT; i++)
#pragma unroll
      for (int j = 0; j < NT; j++)
        acc[i][j] = __builtin_amdgcn_mfma_i32_16x16x64_i8(b1[j], a1[i],
                                                          acc[i][j], 0, 0, 0);
    __builtin_amdgcn_s_setprio(0);
    if (t + 2 < NTILES) {
      VMCNT(4);   // allow A(t+2)'s 4 loads to stay in flight
    } else {
      VMCNT(0);   // tail: everything must land
    }
    SBAR;
  }

  // epilogue (transposed frags: lane holds m = wm+i*16+l15, n = wn+j*16+
  // quad*4+r for r=0..3 — consecutive n -> packed stores)
  float scale = load_scale(scales + sa) * load_scale(scales + sb);
  float lmax = 0.0f;
#pragma unroll
  for (int j = 0; j < NT; j++) {
    long nb = n0 + wn + j * 16 + quad * 4;
    float4 bv = *(const float4*)(bias + nb);
    float4 blr[4][2];
#pragma unroll
    for (int r = 0; r < 4; r++) {
      blr[r][0] = ((const float4*)(Bl + (nb + r) * 8))[0];
      blr[r][1] = ((const float4*)(Bl + (nb + r) * 8))[1];
    }
#pragma unroll
    for (int i = 0; i < MT; i++) {
      long m = m0 + wm + i * 16 + l15;
      float4 t0 = ((const float4*)(tl + m * 8))[0];
      float4 t1v = ((const float4*)(tl + m * 8))[1];
      float vout[4];
#pragma unroll
      for (int r = 0; r < 4; r++) {
        float lora = t0.x * blr[r][0].x + t0.y * blr[r][0].y +
                     t0.z * blr[r][0].z + t0.w * blr[r][0].w +
                     t1v.x * blr[r][1].x + t1v.y * blr[r][1].y +
                     t1v.z * blr[r][1].z + t1v.w * blr[r][1].w;
        float bvr = (r == 0) ? bv.x : (r == 1) ? bv.y : (r == 2) ? bv.z : bv.w;
        vout[r] = (float)acc[i][j][r] * scale + bvr + 2.0f * lora;
      }
      if (MODE == 0) {
        u32 pk[2];
#pragma unroll
        for (int c = 0; c < 2; c++) {
          float h0 = gelu_erf(vout[2 * c]);
          float h1 = gelu_erf(vout[2 * c + 1]);
          lmax = fmaxf(lmax, fmaxf(fabsf(h0), fabsf(h1)));
          __half a = __float2half_rn(h0), b = __float2half_rn(h1);
          pk[c] = (u32)(*(u16*)&a) | ((u32)(*(u16*)&b) << 16);
        }
        uint2 o = {pk[0], pk[1]};
        *(uint2*)((u16*)outp + m * N + nb) = o;
      } else {
        float4 o = {vout[0], vout[1], vout[2], vout[3]};
        *(float4*)((float*)outp + m * N + nb) = o;
      }
    }
  }
  if (MODE == 0) {
    atomicMax(&bmax, __float_as_uint(lmax));
    __syncthreads();
    if (tid == 0) atomicMax(hmax, bmax);
  }
}

extern "C" void kernel_launch(void* const* d_in, const int* in_sizes, int n_in,
                              void* d_out, int out_size, void* d_ws,
                              size_t ws_size, hipStream_t stream) {
  const float* x = (const float*)d_in[0];    // [8192][1024]
  const float* Wfc = (const float*)d_in[1];  // [4096][1024]
  const float* bfc = (const float*)d_in[2];  // [4096]
  const float* Afc = (const float*)d_in[3];  // [8][1024]
  const float* Bfc = (const float*)d_in[4];  // [4096][8]
  const float* Wpr = (const float*)d_in[5];  // [1024][4096]
  const float* bpr = (const float*)d_in[6];  // [1024]
  const float* Apr = (const float*)d_in[7];  // [8][4096]
  const float* Bpr = (const float*)d_in[8];  // [1024][8]
  float* out = (float*)d_out;                // fp32 [8192][1024]

  char* w = (char*)d_ws;
  u32* scales = (u32*)w;                   // 4 slots (fp32 bits): x, Wfc, Wpr, h
  float* t1 = (float*)(w + 256);           // [8192][8]
  float* t2 = (float*)(w + 256 + 262144);  // [8192][8]
  i8* xq = (i8*)(w + 524544);              // [8192][1024] i8
  f16* aprh = (f16*)(w + 8913152);         // [16][4096] fp16
  f16* afch = (f16*)(w + 9175040);         // [16][1024] fp16 (gap before wq1)
  i8* wq1 = (i8*)(w + 9437184);            // [4096][1024] i8
  i8* wq2 = (i8*)(w + 13631488);           // [1024][4096] i8
  u16* hq = (u16*)(w + 17825792);          // [8192][4096] fp16 h; i8 in place
  if (ws_size < 84934656) return;          // need ~81 MiB scratch

  hipMemsetAsync(w, 0, 524544, stream);    // scales + t1 + t2 (atomicAdd'd)
  conv_a16x2_kernel<<<dim3(32, 2), 256, 0, stream>>>(Apr, aprh, Afc, afch);
  absmax3_kernel<<<dim3(512, 3), 256, 0, stream>>>(
      x, 8192 * 1024 / 4, Wfc, 4096 * 1024 / 4, Wpr, 4096 * 1024 / 4, scales);
  quant_x_t1_fused<<<dim3(2, 128), 256, 0, stream>>>(x, afch, scales + 0, xq,
                                                     t1);
  quant_w2_kernel<<<dim3(256, 2), 256, 0, stream>>>(Wfc, Wpr, 4096 * 1024 / 16,
                                                    scales, wq1, wq2);
  // gemm1: 8192x4096, K=1024, BM=256 BN=256, grid (16,32)=512 (%8==0)
  gemm8p_kernel<0, 256, 2><<<dim3(16, 32), 512, 0, stream>>>(
      xq, wq1, 4096, 1024, 1024, 1024, bfc, t1, Bfc, scales, 0, 1, hq,
      scales + 3);
  quant_h_t2_fused<<<dim3(8, 128), 256, 0, stream>>>(hq, aprh, scales + 3, t2);
  // gemm2: 8192x1024, K=4096, BM=256 BN=128, grid (8,32)=256 (%8==0)
  gemm8p_kernel<1, 128, 4><<<dim3(8, 32), 512, 0, stream>>>(
      (const i8*)hq, wq2, 1024, 4096, 8192, 4096, bpr, t2, Bpr, scales, 3, 2,
      out, nullptr);
}

// Round 8
// 295.350 us; speedup vs baseline: 1.3945x; 1.3945x over previous
//
#include <hip/hip_runtime.h>
#include <hip/hip_bf16.h>
#include <hip/hip_fp16.h>
#include <math.h>

// QAT GPT2 MLP + LoRA on MI355X — fp32 in/out.
// Round 13: REVERT the swapped-operand epilogue (round-12 counters: WRITE
// 65.5->274MB, FETCH 38->147MB — per-lane packing put consecutive lanes 8KB
// apart; uncoalesced 8B stores dirty whole sectors + RFO fetches; the
// original n-varies-with-lane layout was the coalesced one). GEMM restored
// to the measured-best round-2 8-phase 256^2 form verbatim (80.5us gemm1:
// normal operand order, scalar-u16/dword epilogue stores = 32B-contiguous
// per 16 lanes, LGKM0 incl. sched_barrier). Kept from round-11: launch
// fusion only (absmax3 / quant_w2 / conv_a16x2 — ran correct this round).
// Fused quant_x_t1 / quant_h_t2 (MFMA LoRA-t, chunked in-place i8) kept.

typedef unsigned short u16;
typedef unsigned int u32;
typedef signed char i8;
typedef int i32x4 __attribute__((ext_vector_type(4)));
typedef _Float16 f16;
typedef f16 f16x8 __attribute__((ext_vector_type(8)));
typedef float f32x4 __attribute__((ext_vector_type(4)));

#define ASYNC16(gp, lp)                                                        \
  __builtin_amdgcn_global_load_lds(                                            \
      (__attribute__((address_space(1))) void*)(gp),                           \
      (__attribute__((address_space(3))) void*)(lp), 16, 0, 0)

#define VMCNT(N) asm volatile("s_waitcnt vmcnt(" #N ")" ::: "memory")
#define LGKM0                                                                  \
  do {                                                                         \
    asm volatile("s_waitcnt lgkmcnt(0)" ::: "memory");                         \
    __builtin_amdgcn_sched_barrier(0);                                         \
  } while (0)
#define SBAR __builtin_amdgcn_s_barrier()

// quantize to int: q = clip(rint(v/s), -128, 127)
__device__ __forceinline__ int quanti(float v, float inv) {
  float q = rintf(v * inv);
  q = fminf(fmaxf(q, -128.0f), 127.0f);
  return (int)q;
}

__device__ __forceinline__ u32 pack4(float4 v, float inv) {
  return ((u32)(quanti(v.x, inv) & 255)) |
         ((u32)(quanti(v.y, inv) & 255) << 8) |
         ((u32)(quanti(v.z, inv) & 255) << 16) |
         ((u32)(quanti(v.w, inv) & 255) << 24);
}

__device__ __forceinline__ float load_scale(const u32* slot) {
  return fmaxf(__uint_as_float(*slot) * (1.0f / 127.0f), 1e-8f);
}

// exact-erf GELU via Abramowitz-Stegun 7.1.26 (|erf err| <= 1.5e-7)
__device__ __forceinline__ float gelu_erf(float v) {
  float z = fabsf(v) * 0.70710678118654752f;
  float t = __builtin_amdgcn_rcpf(fmaf(0.3275911f, z, 1.0f));
  float poly =
      t * fmaf(t,
               fmaf(t,
                    fmaf(t, fmaf(t, 1.061405429f, -1.453152027f),
                         1.421413741f),
                    -0.284496736f),
               0.254829592f);
  float e = fmaf(-poly, exp2f(-z * z * 1.4426950408889634f), 1.0f);
  return 0.5f * v * fmaf(copysignf(e, v), 1.0f, 1.0f);
}

// ---- fused absmax over 3 fp32 tensors (blockIdx.y selects) -----------------
__global__ void absmax3_kernel(const float* __restrict__ t0, int n0,
                               const float* __restrict__ t1, int n1,
                               const float* __restrict__ t2, int n2,
                               u32* __restrict__ slots) {
  const float* x;
  int n4;
  u32* slot;
  if (blockIdx.y == 0) { x = t0; n4 = n0; slot = slots + 0; }
  else if (blockIdx.y == 1) { x = t1; n4 = n1; slot = slots + 1; }
  else { x = t2; n4 = n2; slot = slots + 2; }
  float m = 0.0f;
  int stride = gridDim.x * blockDim.x;
  for (int i = blockIdx.x * blockDim.x + threadIdx.x; i < n4; i += stride) {
    float4 v = ((const float4*)x)[i];
    m = fmaxf(m, fmaxf(fmaxf(fabsf(v.x), fabsf(v.y)),
                       fmaxf(fabsf(v.z), fabsf(v.w))));
  }
#pragma unroll
  for (int off = 32; off > 0; off >>= 1) m = fmaxf(m, __shfl_down(m, off));
  __shared__ float wmax[4];
  int lane = threadIdx.x & 63, wave = threadIdx.x >> 6;
  if (lane == 0) wmax[wave] = m;
  __syncthreads();
  if (threadIdx.x == 0) {
    m = fmaxf(fmaxf(wmax[0], wmax[1]), fmaxf(wmax[2], wmax[3]));
    atomicMax(slot, __float_as_uint(m));  // positive floats: bit-monotone
  }
}

// ---------------- quantize both W (fp32 in, packed i8 out) ------------------
__global__ void quant_w2_kernel(const float* __restrict__ w0,
                                const float* __restrict__ w1, int n16,
                                const u32* __restrict__ slots,
                                i8* __restrict__ q0, i8* __restrict__ q1) {
  const float* w = blockIdx.y ? w1 : w0;
  i8* q = blockIdx.y ? q1 : q0;
  float inv = 1.0f / load_scale(slots + 1 + blockIdx.y);
  int stride = gridDim.x * blockDim.x;
  for (int i = blockIdx.x * blockDim.x + threadIdx.x; i < n16; i += stride) {
    const float4* src = (const float4*)w + i * 4;
    u32 pk[4];
#pragma unroll
    for (int c = 0; c < 4; c++) pk[c] = pack4(src[c], inv);
    uint4 o = {pk[0], pk[1], pk[2], pk[3]};
    ((uint4*)q)[i] = o;
  }
}

// ---- convert both A [8][ncols] fp32 -> [16][ncols] fp16, rows 8-15 zero ----
__global__ void conv_a16x2_kernel(const float* __restrict__ A0,
                                  f16* __restrict__ Ah0,  // ncols 4096
                                  const float* __restrict__ A1,
                                  f16* __restrict__ Ah1) {  // ncols 1024
  const float* A = blockIdx.y ? A1 : A0;
  f16* Ah = blockIdx.y ? Ah1 : Ah0;
  int ncols = blockIdx.y ? 1024 : 4096;
  int i = blockIdx.x * blockDim.x + threadIdx.x;
  int base = i * 8;
  if (base >= 16 * ncols) return;
  if (base < 8 * ncols) {
    float4 v0 = ((const float4*)(A + base))[0];
    float4 v1 = ((const float4*)(A + base))[1];
    f16x8 o = {(f16)v0.x, (f16)v0.y, (f16)v0.z, (f16)v0.w,
               (f16)v1.x, (f16)v1.y, (f16)v1.z, (f16)v1.w};
    *(f16x8*)(Ah + base) = o;
  } else {
    f16x8 z = {};
    *(f16x8*)(Ah + base) = z;
  }
}

// ---- fused: quantize x (fp32 -> i8, exact) + t1 = x.Afc^T via fp16 MFMA ----
__launch_bounds__(256) __global__
    void quant_x_t1_fused(const float* __restrict__ x,   // [8192][1024]
                          const f16* __restrict__ Ah,    // [16][1024]
                          const u32* __restrict__ slot,
                          i8* __restrict__ xq,           // [8192][1024]
                          float* __restrict__ t1) {      // [8192][8], zeroed
  int tid = threadIdx.x;
  int lane = tid & 63, wave = tid >> 6;
  int quad = lane >> 4, l15 = lane & 15;
  int bx = blockIdx.x;                       // k-chunk [0,2)
  long m0 = (long)blockIdx.y * 64 + wave * 16;
  long row = m0 + l15;
  int k0 = bx * 512;
  float inv = 1.0f / load_scale(slot);

  const float* xp = x + row * 1024 + k0 + quad * 8;
  const f16* ap = Ah + l15 * 1024 + k0 + quad * 8;
  i8* op = xq + row * 1024 + k0 + quad * 8;
  f32x4 acc = {0.0f, 0.0f, 0.0f, 0.0f};
#pragma unroll
  for (int s = 0; s < 16; s++) {
    float4 v0 = ((const float4*)(xp + s * 32))[0];
    float4 v1 = ((const float4*)(xp + s * 32))[1];
    f16x8 af = {(f16)v0.x, (f16)v0.y, (f16)v0.z, (f16)v0.w,
                (f16)v1.x, (f16)v1.y, (f16)v1.z, (f16)v1.w};
    f16x8 bf = *(const f16x8*)(ap + s * 32);
    acc = __builtin_amdgcn_mfma_f32_16x16x32_f16(af, bf, acc, 0, 0, 0);
    uint2 o = {pack4(v0, inv), pack4(v1, inv)};
    *(uint2*)(op + s * 32) = o;
  }
  if (l15 < 8) {
#pragma unroll
    for (int r = 0; r < 4; r++) {
      long m = m0 + quad * 4 + r;
      atomicAdd(&t1[m * 8 + l15], acc[r]);
    }
  }
}

// ---- fused: quantize h (fp16 -> i8 in place, chunked) + t2 = h.A^T via MFMA
__launch_bounds__(256) __global__
    void quant_h_t2_fused(u16* __restrict__ h,        // [8192][4096] fp16
                          const f16* __restrict__ Ah, // [16][4096]
                          const u32* __restrict__ slot,
                          float* __restrict__ t2) {   // [8192][8], pre-zeroed
  int tid = threadIdx.x;
  int lane = tid & 63, wave = tid >> 6;
  int quad = lane >> 4, l15 = lane & 15;
  int bx = blockIdx.x;                       // k-chunk index [0,8)
  long m0 = (long)blockIdx.y * 64 + wave * 16;
  long row = m0 + l15;
  int k0 = bx * 512;
  float inv = 1.0f / load_scale(slot);

  const u16* hp = h + row * 4096 + k0 + quad * 8;
  const f16* ap = Ah + l15 * 4096 + k0 + quad * 8;
  f32x4 acc = {0.0f, 0.0f, 0.0f, 0.0f};
  u32 q[32];
#pragma unroll
  for (int s = 0; s < 16; s++) {
    uint4 hv = *(const uint4*)(hp + s * 32);   // 8 fp16 of h
    f16x8 af = *(const f16x8*)&hv;
    f16x8 bf = *(const f16x8*)(ap + s * 32);
    acc = __builtin_amdgcn_mfma_f32_16x16x32_f16(af, bf, acc, 0, 0, 0);
    u32 uu[4] = {hv.x, hv.y, hv.z, hv.w};
#pragma unroll
    for (int c = 0; c < 2; c++) {
      float2 f0 = __half22float2(*(__half2*)&uu[2 * c]);
      float2 f1 = __half22float2(*(__half2*)&uu[2 * c + 1]);
      q[2 * s + c] = ((u32)(quanti(f0.x, inv) & 255)) |
                     ((u32)(quanti(f0.y, inv) & 255) << 8) |
                     ((u32)(quanti(f1.x, inv) & 255) << 16) |
                     ((u32)(quanti(f1.y, inv) & 255) << 24);
    }
  }
  asm volatile("" ::: "memory");
  i8* op = (i8*)h + row * 8192 + bx * 1024 + quad * 8;
#pragma unroll
  for (int s = 0; s < 16; s++) {
    uint2 o = {q[2 * s], q[2 * s + 1]};
    *(uint2*)(op + s * 32) = o;
  }
  if (l15 < 8) {
#pragma unroll
    for (int r = 0; r < 4; r++) {
      long m = m0 + quad * 4 + r;
      atomicAdd(&t2[m * 8 + l15], acc[r]);
    }
  }
}

// ---------- 8-phase pipelined i8 GEMM: C = Aq * Bq^T, BM=256, BK=128 --------
// Round-2 schedule + epilogue verbatim (measured best: 80.5us gemm1).
// C/D layout: lane(quad,l15) holds n = wn+j*16+l15, m = wm+i*16+quad*4+r
// -> u16/dword stores are 16-lane contiguous (32B/64B segments, coalesced).
template <int MODE, int BN, int WARPS_M>
__launch_bounds__(512, 2) __global__
    void gemm8p_kernel(const i8* __restrict__ A, const i8* __restrict__ B,
                       int N, int K, int lda, int ldb,
                       const float* __restrict__ bias,
                       const float* __restrict__ tl,   // [M][8] f32
                       const float* __restrict__ Bl,   // [N][8] f32
                       const u32* __restrict__ scales, int sa, int sb,
                       void* __restrict__ outp, u32* __restrict__ hmax) {
  constexpr int WARPS_N = 8 / WARPS_M;
  constexpr int MT = 256 / (16 * WARPS_M);   // m-tiles per wave
  constexpr int NT = BN / (16 * WARPS_N);    // n-tiles per wave
  constexpr int LB = BN / 128;               // B loads per half per thread
  __shared__ __align__(16) i8 As[2][256 * 128];
  __shared__ __align__(16) i8 Bs[2][BN * 128];
  __shared__ u32 bmax;
  int tid = threadIdx.x;
  int lane = tid & 63, wave = tid >> 6;
  int quad = lane >> 4, l15 = lane & 15;
  int wm = (wave % WARPS_M) * (MT * 16);
  int wn = (wave / WARPS_M) * (NT * 16);
  // XCD-bijective swizzle (nwg % 8 == 0 for both grids)
  int nwg = gridDim.x * gridDim.y;
  int lin = blockIdx.y * gridDim.x + blockIdx.x;
  int swb = (lin & 7) * (nwg >> 3) + (lin >> 3);
  int bx = swb % gridDim.x, by = swb / gridDim.x;
  long m0 = (long)by * 256;
  long n0 = (long)bx * BN;
  if (MODE == 0 && tid == 0) bmax = 0u;

  const i8* pA[2];
  int ldsA[2];
#pragma unroll
  for (int u = 0; u < 2; u++) {
    int c = u * 512 + tid;
    int row = c >> 3;
    int swz = ((c & 7) ^ (row & 7)) * 16;
    pA[u] = A + (m0 + row) * lda + swz;
    ldsA[u] = c * 16;
  }
  const i8* pB[LB];
  int ldsB[LB];
#pragma unroll
  for (int u = 0; u < LB; u++) {
    int c = u * 512 + tid;
    int row = c >> 3;
    int swz = ((c & 7) ^ (row & 7)) * 16;
    pB[u] = B + (n0 + row) * ldb + swz;
    ldsB[u] = c * 16;
  }

  auto stageA = [&](int t, int h) {
    int kb = (MODE == 1) ? ((t >> 2) * 1024 + (t & 3) * 128) : (t << 7);
    int bb = t & 1;
#pragma unroll
    for (int u = 0; u < 2; u++)
      ASYNC16(pA[u] + (long)h * 128 * lda + kb,
              &As[bb][h * 16384 + ldsA[u]]);
  };
  auto stageB = [&](int t, int h) {
    int kb = t << 7;
    int bb = t & 1;
#pragma unroll
    for (int u = 0; u < LB; u++)
      ASYNC16(pB[u] + (long)h * (BN / 2) * ldb + kb,
              &Bs[bb][h * (BN / 2) * 128 + ldsB[u]]);
  };

  // fragment-read swizzled chunk byte offsets: chunk = (kk*4+quad)^(l15&7)
  int s0 = (quad ^ (l15 & 7)) * 16;
  int s1 = s0 ^ 64;

  i32x4 acc[MT][NT] = {};
  int NTILES = K >> 7;

  // prologue: tile0 fully + tile1 A-halves; then wait tile0 (4 may fly)
  stageA(0, 0); stageA(0, 1); stageB(0, 0); stageB(0, 1);
  stageA(1, 0); stageA(1, 1);
  VMCNT(4);
  SBAR;

  for (int t = 0; t < NTILES; t++) {
    const i8* Ab = As[t & 1];
    const i8* Bb = Bs[t & 1];
    i32x4 a0[MT], a1[MT], b0[NT], b1[NT];
    // ---- phase 1: read A[kk0]+B[kk0]; stage B-h0(t+1); MFMA kk0, mhalf0
#pragma unroll
    for (int i = 0; i < MT; i++)
      a0[i] = *(const i32x4*)(Ab + (wm + i * 16 + l15) * 128 + s0);
#pragma unroll
    for (int j = 0; j < NT; j++)
      b0[j] = *(const i32x4*)(Bb + (wn + j * 16 + l15) * 128 + s0);
    if (t + 1 < NTILES) stageB(t + 1, 0);
    SBAR;
    LGKM0;
    __builtin_amdgcn_s_setprio(1);
#pragma unroll
    for (int i = 0; i < MT / 2; i++)
#pragma unroll
      for (int j = 0; j < NT; j++)
        acc[i][j] = __builtin_amdgcn_mfma_i32_16x16x64_i8(a0[i], b0[j],
                                                          acc[i][j], 0, 0, 0);
    __builtin_amdgcn_s_setprio(0);
    SBAR;
    // ---- phase 2: read A[kk1]; stage B-h1(t+1); MFMA kk0, mhalf1
#pragma unroll
    for (int i = 0; i < MT; i++)
      a1[i] = *(const i32x4*)(Ab + (wm + i * 16 + l15) * 128 + s1);
    if (t + 1 < NTILES) stageB(t + 1, 1);
    SBAR;
    LGKM0;
    __builtin_amdgcn_s_setprio(1);
#pragma unroll
    for (int i = MT / 2; i < MT; i++)
#pragma unroll
      for (int j = 0; j < NT; j++)
        acc[i][j] = __builtin_amdgcn_mfma_i32_16x16x64_i8(a0[i], b0[j],
                                                          acc[i][j], 0, 0, 0);
    __builtin_amdgcn_s_setprio(0);
    SBAR;
    // ---- phase 3: read B[kk1]; stage A-h0(t+2); MFMA kk1, mhalf0
#pragma unroll
    for (int j = 0; j < NT; j++)
      b1[j] = *(const i32x4*)(Bb + (wn + j * 16 + l15) * 128 + s1);
    if (t + 2 < NTILES) stageA(t + 2, 0);
    SBAR;
    LGKM0;
    __builtin_amdgcn_s_setprio(1);
#pragma unroll
    for (int i = 0; i < MT / 2; i++)
#pragma unroll
      for (int j = 0; j < NT; j++)
        acc[i][j] = __builtin_amdgcn_mfma_i32_16x16x64_i8(a1[i], b1[j],
                                                          acc[i][j], 0, 0, 0);
    __builtin_amdgcn_s_setprio(0);
    SBAR;
    // ---- phase 4: stage A-h1(t+2); MFMA kk1, mhalf1; counted vmcnt
    if (t + 2 < NTILES) stageA(t + 2, 1);
    SBAR;
    __builtin_amdgcn_s_setprio(1);
#pragma unroll
    for (int i = MT / 2; i < MT; i++)
#pragma unroll
      for (int j = 0; j < NT; j++)
        acc[i][j] = __builtin_amdgcn_mfma_i32_16x16x64_i8(a1[i], b1[j],
                                                          acc[i][j], 0, 0, 0);
    __builtin_amdgcn_s_setprio(0);
    if (t + 2 < NTILES) {
      VMCNT(4);   // allow A(t+2)'s 4 loads to stay in flight
    } else {
      VMCNT(0);   // tail: everything must land
    }
    SBAR;
  }

  // epilogue (original layout: lane holds n = wn+j*16+l15 -> coalesced)
  float scale = load_scale(scales + sa) * load_scale(scales + sb);
  float biasv[NT];
  float4 bl0[NT], bl1[NT];
#pragma unroll
  for (int j = 0; j < NT; j++) {
    long n = n0 + wn + j * 16 + l15;
    biasv[j] = bias[n];
    bl0[j] = ((const float4*)(Bl + n * 8))[0];
    bl1[j] = ((const float4*)(Bl + n * 8))[1];
  }
  float lmax = 0.0f;
#pragma unroll
  for (int i = 0; i < MT; i++) {
#pragma unroll
    for (int r = 0; r < 4; r++) {
      long m = m0 + wm + i * 16 + quad * 4 + r;
      float4 t0 = ((const float4*)(tl + m * 8))[0];
      float4 t1v = ((const float4*)(tl + m * 8))[1];
#pragma unroll
      for (int j = 0; j < NT; j++) {
        long n = n0 + wn + j * 16 + l15;
        float lora = t0.x * bl0[j].x + t0.y * bl0[j].y + t0.z * bl0[j].z +
                     t0.w * bl0[j].w + t1v.x * bl1[j].x + t1v.y * bl1[j].y +
                     t1v.z * bl1[j].z + t1v.w * bl1[j].w;
        float v = (float)acc[i][j][r] * scale + biasv[j] + 2.0f * lora;
        if (MODE == 0) {
          float hv = gelu_erf(v);
          __half hh = __float2half_rn(hv);
          ((u16*)outp)[m * N + n] = *(u16*)&hh;
          lmax = fmaxf(lmax, fabsf(hv));
        } else {
          ((float*)outp)[m * N + n] = v;
        }
      }
    }
  }
  if (MODE == 0) {
    atomicMax(&bmax, __float_as_uint(lmax));
    __syncthreads();
    if (tid == 0) atomicMax(hmax, bmax);
  }
}

extern "C" void kernel_launch(void* const* d_in, const int* in_sizes, int n_in,
                              void* d_out, int out_size, void* d_ws,
                              size_t ws_size, hipStream_t stream) {
  const float* x = (const float*)d_in[0];    // [8192][1024]
  const float* Wfc = (const float*)d_in[1];  // [4096][1024]
  const float* bfc = (const float*)d_in[2];  // [4096]
  const float* Afc = (const float*)d_in[3];  // [8][1024]
  const float* Bfc = (const float*)d_in[4];  // [4096][8]
  const float* Wpr = (const float*)d_in[5];  // [1024][4096]
  const float* bpr = (const float*)d_in[6];  // [1024]
  const float* Apr = (const float*)d_in[7];  // [8][4096]
  const float* Bpr = (const float*)d_in[8];  // [1024][8]
  float* out = (float*)d_out;                // fp32 [8192][1024]

  char* w = (char*)d_ws;
  u32* scales = (u32*)w;                   // 4 slots (fp32 bits): x, Wfc, Wpr, h
  float* t1 = (float*)(w + 256);           // [8192][8]
  float* t2 = (float*)(w + 256 + 262144);  // [8192][8]
  i8* xq = (i8*)(w + 524544);              // [8192][1024] i8
  f16* aprh = (f16*)(w + 8913152);         // [16][4096] fp16
  f16* afch = (f16*)(w + 9175040);         // [16][1024] fp16 (gap before wq1)
  i8* wq1 = (i8*)(w + 9437184);            // [4096][1024] i8
  i8* wq2 = (i8*)(w + 13631488);           // [1024][4096] i8
  u16* hq = (u16*)(w + 17825792);          // [8192][4096] fp16 h; i8 in place
  if (ws_size < 84934656) return;          // need ~81 MiB scratch

  hipMemsetAsync(w, 0, 524544, stream);    // scales + t1 + t2 (atomicAdd'd)
  conv_a16x2_kernel<<<dim3(32, 2), 256, 0, stream>>>(Apr, aprh, Afc, afch);
  absmax3_kernel<<<dim3(512, 3), 256, 0, stream>>>(
      x, 8192 * 1024 / 4, Wfc, 4096 * 1024 / 4, Wpr, 4096 * 1024 / 4, scales);
  quant_x_t1_fused<<<dim3(2, 128), 256, 0, stream>>>(x, afch, scales + 0, xq,
                                                     t1);
  quant_w2_kernel<<<dim3(256, 2), 256, 0, stream>>>(Wfc, Wpr, 4096 * 1024 / 16,
                                                    scales, wq1, wq2);
  // gemm1: 8192x4096, K=1024, BM=256 BN=256, grid (16,32)=512 (%8==0)
  gemm8p_kernel<0, 256, 2><<<dim3(16, 32), 512, 0, stream>>>(
      xq, wq1, 4096, 1024, 1024, 1024, bfc, t1, Bfc, scales, 0, 1, hq,
      scales + 3);
  quant_h_t2_fused<<<dim3(8, 128), 256, 0, stream>>>(hq, aprh, scales + 3, t2);
  // gemm2: 8192x1024, K=4096, BM=256 BN=128, grid (8,32)=256 (%8==0)
  gemm8p_kernel<1, 128, 4><<<dim3(8, 32), 512, 0, stream>>>(
      (const i8*)hq, wq2, 1024, 4096, 8192, 4096, bpr, t2, Bpr, scales, 3, 2,
      out, nullptr);
}

// Round 9
// 285.560 us; speedup vs baseline: 1.4423x; 1.0343x over previous
//
#include <hip/hip_runtime.h>
#include <hip/hip_bf16.h>
#include <hip/hip_fp16.h>
#include <math.h>

// QAT GPT2 MLP + LoRA on MI355X — fp32 in/out.
// Round 14: round-8 banked 295.3us (best). Profile pass that round was
// throttled (identical GEMM code+bytes, all rates x0.6) -> dur_us is the
// arbiter. GEMM schedule ledger closed at ~80us/gemm (5 structures tried);
// remaining lever = dispatch overhead (~65us across 8 launches + memset).
// This round: pure launch fusion, GEMMs byte-identical to round-8:
//   absmax4 = absmax3 + conv_a16x2 as 4th y-plane (independent work).
//   quant_all = quant_x_t1_fused + quant_w2 via y-plane selector.
// 8 dispatches -> 6. No math changes anywhere.

typedef unsigned short u16;
typedef unsigned int u32;
typedef signed char i8;
typedef int i32x4 __attribute__((ext_vector_type(4)));
typedef _Float16 f16;
typedef f16 f16x8 __attribute__((ext_vector_type(8)));
typedef float f32x4 __attribute__((ext_vector_type(4)));

#define ASYNC16(gp, lp)                                                        \
  __builtin_amdgcn_global_load_lds(                                            \
      (__attribute__((address_space(1))) void*)(gp),                           \
      (__attribute__((address_space(3))) void*)(lp), 16, 0, 0)

#define VMCNT(N) asm volatile("s_waitcnt vmcnt(" #N ")" ::: "memory")
#define LGKM0                                                                  \
  do {                                                                         \
    asm volatile("s_waitcnt lgkmcnt(0)" ::: "memory");                         \
    __builtin_amdgcn_sched_barrier(0);                                         \
  } while (0)
#define SBAR __builtin_amdgcn_s_barrier()

// quantize to int: q = clip(rint(v/s), -128, 127)
__device__ __forceinline__ int quanti(float v, float inv) {
  float q = rintf(v * inv);
  q = fminf(fmaxf(q, -128.0f), 127.0f);
  return (int)q;
}

__device__ __forceinline__ u32 pack4(float4 v, float inv) {
  return ((u32)(quanti(v.x, inv) & 255)) |
         ((u32)(quanti(v.y, inv) & 255) << 8) |
         ((u32)(quanti(v.z, inv) & 255) << 16) |
         ((u32)(quanti(v.w, inv) & 255) << 24);
}

__device__ __forceinline__ float load_scale(const u32* slot) {
  return fmaxf(__uint_as_float(*slot) * (1.0f / 127.0f), 1e-8f);
}

// exact-erf GELU via Abramowitz-Stegun 7.1.26 (|erf err| <= 1.5e-7)
__device__ __forceinline__ float gelu_erf(float v) {
  float z = fabsf(v) * 0.70710678118654752f;
  float t = __builtin_amdgcn_rcpf(fmaf(0.3275911f, z, 1.0f));
  float poly =
      t * fmaf(t,
               fmaf(t,
                    fmaf(t, fmaf(t, 1.061405429f, -1.453152027f),
                         1.421413741f),
                    -0.284496736f),
               0.254829592f);
  float e = fmaf(-poly, exp2f(-z * z * 1.4426950408889634f), 1.0f);
  return 0.5f * v * fmaf(copysignf(e, v), 1.0f, 1.0f);
}

// ---- fused: absmax over 3 fp32 tensors (y=0..2) + A fp32->fp16 conv (y=3) --
__global__ void absmax4_kernel(const float* __restrict__ t0, int n0,
                               const float* __restrict__ t1, int n1,
                               const float* __restrict__ t2, int n2,
                               u32* __restrict__ slots,
                               const float* __restrict__ Apr,
                               f16* __restrict__ aprh,   // [16][4096]
                               const float* __restrict__ Afc,
                               f16* __restrict__ afch) { // [16][1024]
  if (blockIdx.y == 3) {
    // conv plane: 8192 f16x8 for aprh, 2048 for afch; extra blocks exit.
    int i = blockIdx.x * blockDim.x + threadIdx.x;
    if (i >= 8192 + 2048) return;
    const float* A;
    f16* Ah;
    int ncols, ii;
    if (i < 8192) { A = Apr; Ah = aprh; ncols = 4096; ii = i; }
    else          { A = Afc; Ah = afch; ncols = 1024; ii = i - 8192; }
    int base = ii * 8;
    if (base < 8 * ncols) {
      float4 v0 = ((const float4*)(A + base))[0];
      float4 v1 = ((const float4*)(A + base))[1];
      f16x8 o = {(f16)v0.x, (f16)v0.y, (f16)v0.z, (f16)v0.w,
                 (f16)v1.x, (f16)v1.y, (f16)v1.z, (f16)v1.w};
      *(f16x8*)(Ah + base) = o;
    } else {
      f16x8 z = {};
      *(f16x8*)(Ah + base) = z;
    }
    return;
  }
  const float* x;
  int n4;
  u32* slot;
  if (blockIdx.y == 0) { x = t0; n4 = n0; slot = slots + 0; }
  else if (blockIdx.y == 1) { x = t1; n4 = n1; slot = slots + 1; }
  else { x = t2; n4 = n2; slot = slots + 2; }
  float m = 0.0f;
  int stride = gridDim.x * blockDim.x;
  for (int i = blockIdx.x * blockDim.x + threadIdx.x; i < n4; i += stride) {
    float4 v = ((const float4*)x)[i];
    m = fmaxf(m, fmaxf(fmaxf(fabsf(v.x), fabsf(v.y)),
                       fmaxf(fabsf(v.z), fabsf(v.w))));
  }
#pragma unroll
  for (int off = 32; off > 0; off >>= 1) m = fmaxf(m, __shfl_down(m, off));
  __shared__ float wmax[4];
  int lane = threadIdx.x & 63, wave = threadIdx.x >> 6;
  if (lane == 0) wmax[wave] = m;
  __syncthreads();
  if (threadIdx.x == 0) {
    m = fmaxf(fmaxf(wmax[0], wmax[1]), fmaxf(wmax[2], wmax[3]));
    atomicMax(slot, __float_as_uint(m));  // positive floats: bit-monotone
  }
}

// ---- fused: quantize x + t1 (y=0) | quantize Wfc (y=1) | quantize Wpr (y=2)
__launch_bounds__(256) __global__
    void quant_all_kernel(const float* __restrict__ x,   // [8192][1024]
                          const f16* __restrict__ Ah,    // [16][1024]
                          const u32* __restrict__ slots,
                          i8* __restrict__ xq,           // [8192][1024]
                          float* __restrict__ t1,        // [8192][8], zeroed
                          const float* __restrict__ Wfc,
                          const float* __restrict__ Wpr,
                          i8* __restrict__ wq1, i8* __restrict__ wq2) {
  int tid = threadIdx.x;
  if (blockIdx.y != 0) {
    // quant_w plane: grid-stride over 4096*1024/16 uint4 chunks
    const float* w = (blockIdx.y == 1) ? Wfc : Wpr;
    i8* q = (blockIdx.y == 1) ? wq1 : wq2;
    float inv = 1.0f / load_scale(slots + blockIdx.y);  // slot 1 or 2
    int n16 = 4096 * 1024 / 16;
    int stride = gridDim.x * blockDim.x;
    for (int i = blockIdx.x * blockDim.x + tid; i < n16; i += stride) {
      const float4* src = (const float4*)w + i * 4;
      u32 pk[4];
#pragma unroll
      for (int c = 0; c < 4; c++) pk[c] = pack4(src[c], inv);
      uint4 o = {pk[0], pk[1], pk[2], pk[3]};
      ((uint4*)q)[i] = o;
    }
    return;
  }
  // quant_x + t1 plane: 256 blocks -> bx = x&1 (k-chunk), by = x>>1 (m-group)
  int lane = tid & 63, wave = tid >> 6;
  int quad = lane >> 4, l15 = lane & 15;
  int bx = blockIdx.x & 1;
  long m0 = (long)(blockIdx.x >> 1) * 64 + wave * 16;
  long row = m0 + l15;
  int k0 = bx * 512;
  float inv = 1.0f / load_scale(slots + 0);

  const float* xp = x + row * 1024 + k0 + quad * 8;
  const f16* ap = Ah + l15 * 1024 + k0 + quad * 8;
  i8* op = xq + row * 1024 + k0 + quad * 8;
  f32x4 acc = {0.0f, 0.0f, 0.0f, 0.0f};
#pragma unroll
  for (int s = 0; s < 16; s++) {
    float4 v0 = ((const float4*)(xp + s * 32))[0];
    float4 v1 = ((const float4*)(xp + s * 32))[1];
    f16x8 af = {(f16)v0.x, (f16)v0.y, (f16)v0.z, (f16)v0.w,
                (f16)v1.x, (f16)v1.y, (f16)v1.z, (f16)v1.w};
    f16x8 bf = *(const f16x8*)(ap + s * 32);
    acc = __builtin_amdgcn_mfma_f32_16x16x32_f16(af, bf, acc, 0, 0, 0);
    uint2 o = {pack4(v0, inv), pack4(v1, inv)};
    *(uint2*)(op + s * 32) = o;
  }
  if (l15 < 8) {
#pragma unroll
    for (int r = 0; r < 4; r++) {
      long m = m0 + quad * 4 + r;
      atomicAdd(&t1[m * 8 + l15], acc[r]);
    }
  }
}

// ---- fused: quantize h (fp16 -> i8 in place, chunked) + t2 = h.A^T via MFMA
__launch_bounds__(256) __global__
    void quant_h_t2_fused(u16* __restrict__ h,        // [8192][4096] fp16
                          const f16* __restrict__ Ah, // [16][4096]
                          const u32* __restrict__ slot,
                          float* __restrict__ t2) {   // [8192][8], pre-zeroed
  int tid = threadIdx.x;
  int lane = tid & 63, wave = tid >> 6;
  int quad = lane >> 4, l15 = lane & 15;
  int bx = blockIdx.x;                       // k-chunk index [0,8)
  long m0 = (long)blockIdx.y * 64 + wave * 16;
  long row = m0 + l15;
  int k0 = bx * 512;
  float inv = 1.0f / load_scale(slot);

  const u16* hp = h + row * 4096 + k0 + quad * 8;
  const f16* ap = Ah + l15 * 4096 + k0 + quad * 8;
  f32x4 acc = {0.0f, 0.0f, 0.0f, 0.0f};
  u32 q[32];
#pragma unroll
  for (int s = 0; s < 16; s++) {
    uint4 hv = *(const uint4*)(hp + s * 32);   // 8 fp16 of h
    f16x8 af = *(const f16x8*)&hv;
    f16x8 bf = *(const f16x8*)(ap + s * 32);
    acc = __builtin_amdgcn_mfma_f32_16x16x32_f16(af, bf, acc, 0, 0, 0);
    u32 uu[4] = {hv.x, hv.y, hv.z, hv.w};
#pragma unroll
    for (int c = 0; c < 2; c++) {
      float2 f0 = __half22float2(*(__half2*)&uu[2 * c]);
      float2 f1 = __half22float2(*(__half2*)&uu[2 * c + 1]);
      q[2 * s + c] = ((u32)(quanti(f0.x, inv) & 255)) |
                     ((u32)(quanti(f0.y, inv) & 255) << 8) |
                     ((u32)(quanti(f1.x, inv) & 255) << 16) |
                     ((u32)(quanti(f1.y, inv) & 255) << 24);
    }
  }
  asm volatile("" ::: "memory");
  i8* op = (i8*)h + row * 8192 + bx * 1024 + quad * 8;
#pragma unroll
  for (int s = 0; s < 16; s++) {
    uint2 o = {q[2 * s], q[2 * s + 1]};
    *(uint2*)(op + s * 32) = o;
  }
  if (l15 < 8) {
#pragma unroll
    for (int r = 0; r < 4; r++) {
      long m = m0 + quad * 4 + r;
      atomicAdd(&t2[m * 8 + l15], acc[r]);
    }
  }
}

// ---------- 8-phase pipelined i8 GEMM: C = Aq * Bq^T, BM=256, BK=128 --------
// Round-2 schedule + epilogue verbatim (measured best: 80.5us gemm1).
// C/D layout: lane(quad,l15) holds n = wn+j*16+l15, m = wm+i*16+quad*4+r
// -> u16/dword stores are 16-lane contiguous (32B/64B segments, coalesced).
template <int MODE, int BN, int WARPS_M>
__launch_bounds__(512, 2) __global__
    void gemm8p_kernel(const i8* __restrict__ A, const i8* __restrict__ B,
                       int N, int K, int lda, int ldb,
                       const float* __restrict__ bias,
                       const float* __restrict__ tl,   // [M][8] f32
                       const float* __restrict__ Bl,   // [N][8] f32
                       const u32* __restrict__ scales, int sa, int sb,
                       void* __restrict__ outp, u32* __restrict__ hmax) {
  constexpr int WARPS_N = 8 / WARPS_M;
  constexpr int MT = 256 / (16 * WARPS_M);   // m-tiles per wave
  constexpr int NT = BN / (16 * WARPS_N);    // n-tiles per wave
  constexpr int LB = BN / 128;               // B loads per half per thread
  __shared__ __align__(16) i8 As[2][256 * 128];
  __shared__ __align__(16) i8 Bs[2][BN * 128];
  __shared__ u32 bmax;
  int tid = threadIdx.x;
  int lane = tid & 63, wave = tid >> 6;
  int quad = lane >> 4, l15 = lane & 15;
  int wm = (wave % WARPS_M) * (MT * 16);
  int wn = (wave / WARPS_M) * (NT * 16);
  // XCD-bijective swizzle (nwg % 8 == 0 for both grids)
  int nwg = gridDim.x * gridDim.y;
  int lin = blockIdx.y * gridDim.x + blockIdx.x;
  int swb = (lin & 7) * (nwg >> 3) + (lin >> 3);
  int bx = swb % gridDim.x, by = swb / gridDim.x;
  long m0 = (long)by * 256;
  long n0 = (long)bx * BN;
  if (MODE == 0 && tid == 0) bmax = 0u;

  const i8* pA[2];
  int ldsA[2];
#pragma unroll
  for (int u = 0; u < 2; u++) {
    int c = u * 512 + tid;
    int row = c >> 3;
    int swz = ((c & 7) ^ (row & 7)) * 16;
    pA[u] = A + (m0 + row) * lda + swz;
    ldsA[u] = c * 16;
  }
  const i8* pB[LB];
  int ldsB[LB];
#pragma unroll
  for (int u = 0; u < LB; u++) {
    int c = u * 512 + tid;
    int row = c >> 3;
    int swz = ((c & 7) ^ (row & 7)) * 16;
    pB[u] = B + (n0 + row) * ldb + swz;
    ldsB[u] = c * 16;
  }

  auto stageA = [&](int t, int h) {
    int kb = (MODE == 1) ? ((t >> 2) * 1024 + (t & 3) * 128) : (t << 7);
    int bb = t & 1;
#pragma unroll
    for (int u = 0; u < 2; u++)
      ASYNC16(pA[u] + (long)h * 128 * lda + kb,
              &As[bb][h * 16384 + ldsA[u]]);
  };
  auto stageB = [&](int t, int h) {
    int kb = t << 7;
    int bb = t & 1;
#pragma unroll
    for (int u = 0; u < LB; u++)
      ASYNC16(pB[u] + (long)h * (BN / 2) * ldb + kb,
              &Bs[bb][h * (BN / 2) * 128 + ldsB[u]]);
  };

  // fragment-read swizzled chunk byte offsets: chunk = (kk*4+quad)^(l15&7)
  int s0 = (quad ^ (l15 & 7)) * 16;
  int s1 = s0 ^ 64;

  i32x4 acc[MT][NT] = {};
  int NTILES = K >> 7;

  // prologue: tile0 fully + tile1 A-halves; then wait tile0 (4 may fly)
  stageA(0, 0); stageA(0, 1); stageB(0, 0); stageB(0, 1);
  stageA(1, 0); stageA(1, 1);
  VMCNT(4);
  SBAR;

  for (int t = 0; t < NTILES; t++) {
    const i8* Ab = As[t & 1];
    const i8* Bb = Bs[t & 1];
    i32x4 a0[MT], a1[MT], b0[NT], b1[NT];
    // ---- phase 1: read A[kk0]+B[kk0]; stage B-h0(t+1); MFMA kk0, mhalf0
#pragma unroll
    for (int i = 0; i < MT; i++)
      a0[i] = *(const i32x4*)(Ab + (wm + i * 16 + l15) * 128 + s0);
#pragma unroll
    for (int j = 0; j < NT; j++)
      b0[j] = *(const i32x4*)(Bb + (wn + j * 16 + l15) * 128 + s0);
    if (t + 1 < NTILES) stageB(t + 1, 0);
    SBAR;
    LGKM0;
    __builtin_amdgcn_s_setprio(1);
#pragma unroll
    for (int i = 0; i < MT / 2; i++)
#pragma unroll
      for (int j = 0; j < NT; j++)
        acc[i][j] = __builtin_amdgcn_mfma_i32_16x16x64_i8(a0[i], b0[j],
                                                          acc[i][j], 0, 0, 0);
    __builtin_amdgcn_s_setprio(0);
    SBAR;
    // ---- phase 2: read A[kk1]; stage B-h1(t+1); MFMA kk0, mhalf1
#pragma unroll
    for (int i = 0; i < MT; i++)
      a1[i] = *(const i32x4*)(Ab + (wm + i * 16 + l15) * 128 + s1);
    if (t + 1 < NTILES) stageB(t + 1, 1);
    SBAR;
    LGKM0;
    __builtin_amdgcn_s_setprio(1);
#pragma unroll
    for (int i = MT / 2; i < MT; i++)
#pragma unroll
      for (int j = 0; j < NT; j++)
        acc[i][j] = __builtin_amdgcn_mfma_i32_16x16x64_i8(a0[i], b0[j],
                                                          acc[i][j], 0, 0, 0);
    __builtin_amdgcn_s_setprio(0);
    SBAR;
    // ---- phase 3: read B[kk1]; stage A-h0(t+2); MFMA kk1, mhalf0
#pragma unroll
    for (int j = 0; j < NT; j++)
      b1[j] = *(const i32x4*)(Bb + (wn + j * 16 + l15) * 128 + s1);
    if (t + 2 < NTILES) stageA(t + 2, 0);
    SBAR;
    LGKM0;
    __builtin_amdgcn_s_setprio(1);
#pragma unroll
    for (int i = 0; i < MT / 2; i++)
#pragma unroll
      for (int j = 0; j < NT; j++)
        acc[i][j] = __builtin_amdgcn_mfma_i32_16x16x64_i8(a1[i], b1[j],
                                                          acc[i][j], 0, 0, 0);
    __builtin_amdgcn_s_setprio(0);
    SBAR;
    // ---- phase 4: stage A-h1(t+2); MFMA kk1, mhalf1; counted vmcnt
    if (t + 2 < NTILES) stageA(t + 2, 1);
    SBAR;
    __builtin_amdgcn_s_setprio(1);
#pragma unroll
    for (int i = MT / 2; i < MT; i++)
#pragma unroll
      for (int j = 0; j < NT; j++)
        acc[i][j] = __builtin_amdgcn_mfma_i32_16x16x64_i8(a1[i], b1[j],
                                                          acc[i][j], 0, 0, 0);
    __builtin_amdgcn_s_setprio(0);
    if (t + 2 < NTILES) {
      VMCNT(4);   // allow A(t+2)'s 4 loads to stay in flight
    } else {
      VMCNT(0);   // tail: everything must land
    }
    SBAR;
  }

  // epilogue (original layout: lane holds n = wn+j*16+l15 -> coalesced)
  float scale = load_scale(scales + sa) * load_scale(scales + sb);
  float biasv[NT];
  float4 bl0[NT], bl1[NT];
#pragma unroll
  for (int j = 0; j < NT; j++) {
    long n = n0 + wn + j * 16 + l15;
    biasv[j] = bias[n];
    bl0[j] = ((const float4*)(Bl + n * 8))[0];
    bl1[j] = ((const float4*)(Bl + n * 8))[1];
  }
  float lmax = 0.0f;
#pragma unroll
  for (int i = 0; i < MT; i++) {
#pragma unroll
    for (int r = 0; r < 4; r++) {
      long m = m0 + wm + i * 16 + quad * 4 + r;
      float4 t0 = ((const float4*)(tl + m * 8))[0];
      float4 t1v = ((const float4*)(tl + m * 8))[1];
#pragma unroll
      for (int j = 0; j < NT; j++) {
        long n = n0 + wn + j * 16 + l15;
        float lora = t0.x * bl0[j].x + t0.y * bl0[j].y + t0.z * bl0[j].z +
                     t0.w * bl0[j].w + t1v.x * bl1[j].x + t1v.y * bl1[j].y +
                     t1v.z * bl1[j].z + t1v.w * bl1[j].w;
        float v = (float)acc[i][j][r] * scale + biasv[j] + 2.0f * lora;
        if (MODE == 0) {
          float hv = gelu_erf(v);
          __half hh = __float2half_rn(hv);
          ((u16*)outp)[m * N + n] = *(u16*)&hh;
          lmax = fmaxf(lmax, fabsf(hv));
        } else {
          ((float*)outp)[m * N + n] = v;
        }
      }
    }
  }
  if (MODE == 0) {
    atomicMax(&bmax, __float_as_uint(lmax));
    __syncthreads();
    if (tid == 0) atomicMax(hmax, bmax);
  }
}

extern "C" void kernel_launch(void* const* d_in, const int* in_sizes, int n_in,
                              void* d_out, int out_size, void* d_ws,
                              size_t ws_size, hipStream_t stream) {
  const float* x = (const float*)d_in[0];    // [8192][1024]
  const float* Wfc = (const float*)d_in[1];  // [4096][1024]
  const float* bfc = (const float*)d_in[2];  // [4096]
  const float* Afc = (const float*)d_in[3];  // [8][1024]
  const float* Bfc = (const float*)d_in[4];  // [4096][8]
  const float* Wpr = (const float*)d_in[5];  // [1024][4096]
  const float* bpr = (const float*)d_in[6];  // [1024]
  const float* Apr = (const float*)d_in[7];  // [8][4096]
  const float* Bpr = (const float*)d_in[8];  // [1024][8]
  float* out = (float*)d_out;                // fp32 [8192][1024]

  char* w = (char*)d_ws;
  u32* scales = (u32*)w;                   // 4 slots (fp32 bits): x, Wfc, Wpr, h
  float* t1 = (float*)(w + 256);           // [8192][8]
  float* t2 = (float*)(w + 256 + 262144);  // [8192][8]
  i8* xq = (i8*)(w + 524544);              // [8192][1024] i8
  f16* aprh = (f16*)(w + 8913152);         // [16][4096] fp16
  f16* afch = (f16*)(w + 9175040);         // [16][1024] fp16 (gap before wq1)
  i8* wq1 = (i8*)(w + 9437184);            // [4096][1024] i8
  i8* wq2 = (i8*)(w + 13631488);           // [1024][4096] i8
  u16* hq = (u16*)(w + 17825792);          // [8192][4096] fp16 h; i8 in place
  if (ws_size < 84934656) return;          // need ~81 MiB scratch

  hipMemsetAsync(w, 0, 524544, stream);    // scales + t1 + t2 (atomicAdd'd)
  // absmax(x, Wfc, Wpr) planes 0-2 + A-matrix fp16 conv plane 3
  absmax4_kernel<<<dim3(512, 4), 256, 0, stream>>>(
      x, 8192 * 1024 / 4, Wfc, 4096 * 1024 / 4, Wpr, 4096 * 1024 / 4, scales,
      Apr, aprh, Afc, afch);
  // quant x + t1 (plane 0) | quant Wfc (plane 1) | quant Wpr (plane 2)
  quant_all_kernel<<<dim3(256, 3), 256, 0, stream>>>(x, afch, scales, xq, t1,
                                                     Wfc, Wpr, wq1, wq2);
  // gemm1: 8192x4096, K=1024, BM=256 BN=256, grid (16,32)=512 (%8==0)
  gemm8p_kernel<0, 256, 2><<<dim3(16, 32), 512, 0, stream>>>(
      xq, wq1, 4096, 1024, 1024, 1024, bfc, t1, Bfc, scales, 0, 1, hq,
      scales + 3);
  quant_h_t2_fused<<<dim3(8, 128), 256, 0, stream>>>(hq, aprh, scales + 3, t2);
  // gemm2: 8192x1024, K=4096, BM=256 BN=128, grid (8,32)=256 (%8==0)
  gemm8p_kernel<1, 128, 4><<<dim3(8, 32), 512, 0, stream>>>(
      (const i8*)hq, wq2, 1024, 4096, 8192, 4096, bpr, t2, Bpr, scales, 3, 2,
      out, nullptr);
}